// Round 9
// baseline (382.159 us; speedup 1.0000x reference)
//
#include <hip/hip_runtime.h>

#define NB 131072
#define NEG9 -1e9f

typedef __attribute__((ext_vector_type(8))) __bf16 bf16x8;
typedef __attribute__((ext_vector_type(4))) float f32x4;
typedef __attribute__((ext_vector_type(2))) unsigned int u32x2;
typedef __attribute__((ext_vector_type(4))) unsigned int u32x4;

__device__ __forceinline__ f32x4 mfma16(bf16x8 a, bf16x8 b, f32x4 c) {
    return __builtin_amdgcn_mfma_f32_16x16x32_bf16(a, b, c, 0, 0, 0);
}

// pack two floats to bf16x2 (truncation) in ONE v_perm_b32: [hi16(h) | hi16(l)]
__device__ __forceinline__ unsigned pk(float h, float l) {
    return __builtin_amdgcn_perm(__builtin_bit_cast(unsigned, h),
                                 __builtin_bit_cast(unsigned, l), 0x07060302u);
}
__device__ __forceinline__ unsigned pku(unsigned h, unsigned l) {
    return __builtin_amdgcn_perm(h, l, 0x07060302u);
}

// float -> bf16 (RNE) for weight prep
__device__ __forceinline__ unsigned short f2bf(float f) {
    unsigned u = __builtin_bit_cast(unsigned, f);
    u += 0x7fffu + ((u >> 16) & 1u);
    return (unsigned short)(u >> 16);
}

// BN-folded, transposed (n-major, k-contiguous) bf16 weights + fp32 biases.
struct __align__(16) Wspace {
    unsigned short W0t[512][64];
    unsigned short W1t[256][512];
    unsigned short nW1t[64][256];
    unsigned short dW1t[64][256];
    unsigned short nW2t[128][64];
    unsigned short dW2t[128][64];
    float c0[512];
    float c1[256];
    float nb1c[64], db1c[64];
    float nb2c[128], db2c[128];
};

__device__ Wspace g_ws;

// r11 prep: 64x64 LDS-transpose tiles, fully coalesced both sides (kept).
__global__ __launch_bounds__(256) void prep_kernel(
    const float* __restrict__ W0, const float* __restrict__ b0,
    const float* __restrict__ g0, const float* __restrict__ be0,
    const float* __restrict__ rm0, const float* __restrict__ rv0,
    const float* __restrict__ W1, const float* __restrict__ b1,
    const float* __restrict__ g1, const float* __restrict__ be1,
    const float* __restrict__ rm1, const float* __restrict__ rv1,
    const float* __restrict__ nW1, const float* __restrict__ nb1,
    const float* __restrict__ nW2, const float* __restrict__ nb2,
    const float* __restrict__ dW1, const float* __restrict__ db1,
    const float* __restrict__ dW2, const float* __restrict__ db2)
{
    const int b = blockIdx.x;
    const int t = threadIdx.x;

    if (b == 52) {  // bias / BN-constant vectors (all coalesced)
        {   // c0[512]
            int i = t;          g_ws.c0[i] = (b0[i] - rm0[i]) * (g0[i] * rsqrtf(rv0[i] + 1e-5f)) + be0[i];
            i = t + 256;        g_ws.c0[i] = (b0[i] - rm0[i]) * (g0[i] * rsqrtf(rv0[i] + 1e-5f)) + be0[i];
        }
        g_ws.c1[t] = (b1[t] - rm1[t]) * (g1[t] * rsqrtf(rv1[t] + 1e-5f)) + be1[t];
        if (t < 64)  { g_ws.nb1c[t] = nb1[t]; g_ws.db1c[t] = db1[t]; }
        if (t < 128) { g_ws.nb2c[t] = nb2[t]; g_ws.db2c[t] = db2[t]; }
        return;
    }

    const float* src; unsigned short* dst;
    const float* gp = nullptr; const float* rvp = nullptr;
    int sld, dld, k0, n0;
    if (b < 32)      { src = W1;  dst = (unsigned short*)g_ws.W1t;  sld = 256; dld = 512;
                       k0 = (b >> 2) * 64; n0 = (b & 3) * 64; gp = g1; rvp = rv1; }
    else if (b < 40) { src = W0;  dst = (unsigned short*)g_ws.W0t;  sld = 512; dld = 64;
                       k0 = 0; n0 = (b - 32) * 64; gp = g0; rvp = rv0; }
    else if (b < 44) { src = nW1; dst = (unsigned short*)g_ws.nW1t; sld = 64;  dld = 256;
                       k0 = (b - 40) * 64; n0 = 0; }
    else if (b < 48) { src = dW1; dst = (unsigned short*)g_ws.dW1t; sld = 64;  dld = 256;
                       k0 = (b - 44) * 64; n0 = 0; }
    else if (b < 50) { src = nW2; dst = (unsigned short*)g_ws.nW2t; sld = 128; dld = 64;
                       k0 = 0; n0 = (b - 48) * 64; }
    else             { src = dW2; dst = (unsigned short*)g_ws.dW2t; sld = 128; dld = 64;
                       k0 = 0; n0 = (b - 50) * 64; }

    __shared__ unsigned short tile[64][66];

    const int rr = t >> 4;
    const int cc = (t & 15) * 4;

#pragma unroll
    for (int g = 0; g < 4; ++g) {
        const int r = rr + g * 16;
        f32x4 v = *(const f32x4*)&src[(size_t)(k0 + r) * sld + n0 + cc];
        if (gp) {
            f32x4 gv = *(const f32x4*)&gp[n0 + cc];
            f32x4 rv = *(const f32x4*)&rvp[n0 + cc];
            v[0] *= gv[0] * rsqrtf(rv[0] + 1e-5f);
            v[1] *= gv[1] * rsqrtf(rv[1] + 1e-5f);
            v[2] *= gv[2] * rsqrtf(rv[2] + 1e-5f);
            v[3] *= gv[3] * rsqrtf(rv[3] + 1e-5f);
        }
        *(unsigned*)&tile[r][cc]     = (unsigned)f2bf(v[0]) | ((unsigned)f2bf(v[1]) << 16);
        *(unsigned*)&tile[r][cc + 2] = (unsigned)f2bf(v[2]) | ((unsigned)f2bf(v[3]) << 16);
    }
    __syncthreads();

#pragma unroll
    for (int g = 0; g < 4; ++g) {
        const int n = rr + g * 16;
        unsigned o01 = (unsigned)tile[cc + 0][n] | ((unsigned)tile[cc + 1][n] << 16);
        unsigned o23 = (unsigned)tile[cc + 2][n] | ((unsigned)tile[cc + 3][n] << 16);
        u32x2 o = { o01, o23 };
        *(u32x2*)&dst[(size_t)(n0 + n) * dld + k0 + cc] = o;
    }
}

// LEDGER: fused ~135us robust vs occupancy(44/58/78%), LDS(40-73KB), LDS
//   traffic(-40%), barriers(8->6), ILP/4-wave(r12: 146, worse). Sum of pipes
//   (MFMA 16 + LDS 31 + L2 ~19 + VALU 15) ~= wall => pipes run SEQUENTIALLY:
//   every wave is in the same resource-homogeneous burst between barriers.
// r13: TWO-STREAM PHASE PIPELINE. 64 rows = streams A(0-31)/B(32-63), skewed
//   one phase; each barrier-to-barrier region pairs complementary phases:
//   P2 L0A | P3 L1A(LDS+L2)||L0B(reg-MFMA) | P4 H1A(VALU)||L1B |
//   P5 H1B||head1A | P6 A_A||head1B | P7 A_B||head2A | P8 head2B.
//   Granule scheme identical to r10 but row-stride 32 within each 32KB
//   stream region; H1 overlays [0,16K), A overlays [16K,24K) after reads
//   (barrier-separated). LDS 8+64=73728B (=r10) -> 2 blocks/CU.
//   Spill tripwire: FETCH>25MB / WRITE>140MB.
__global__ __launch_bounds__(512, 4) void fused_mlp(
    const u32x4* __restrict__ xu, float* __restrict__ out)
{
    __shared__ __align__(16) unsigned short sXs[8 * 64 * 8];       //  8 KB (X, live to end)
    __shared__ __align__(16) unsigned short sH0[2 * 64 * 32 * 8];  // 64 KB: 2 stream regions

    const int tid = threadIdx.x;
    const int w = tid >> 6;          // wave 0..7
    const int lane = tid & 63;
    const int m = lane & 15;
    const int q = lane >> 4;
    const int qh = q >> 1;
    const int ql = (q & 1) * 4;
    const int row0 = blockIdx.x * 64;

    unsigned short* const sA = sH0;            // stream A region (16384 shorts)
    unsigned short* const sB = sH0 + 16384;    // stream B region

    // ---- P1: stage X -> bf16 granule-major [g][r][8] ----
    {
        int r = tid >> 3, g = tid & 7;
        u32x4 v0 = __builtin_nontemporal_load(&xu[(size_t)(row0 + r) * 16 + g * 2]);
        u32x4 v1 = __builtin_nontemporal_load(&xu[(size_t)(row0 + r) * 16 + g * 2 + 1]);
        u32x4 p = { pku(v0[1], v0[0]), pku(v0[3], v0[2]), pku(v1[1], v1[0]), pku(v1[3], v1[2]) };
        *(u32x4*)&sXs[(g * 64 + r) * 8] = p;
    }
    __syncthreads();   // B1

    const int head = w >> 2;

    // ---- P2: L0(A): rows 0-31, wave w -> cols [w*64,+64) ----
    {
        bf16x8 xrA[2][2];
#pragma unroll
        for (int g2 = 0; g2 < 2; ++g2)
#pragma unroll
            for (int mt = 0; mt < 2; ++mt)
                xrA[g2][mt] = *(const bf16x8*)&sXs[((g2 * 4 + q) * 64 + mt * 16 + m) * 8];
#pragma unroll
        for (int nt = 0; nt < 4; ++nt) {
            const int gcb = w * 64 + nt * 16;
            bf16x8 wa0 = *(const bf16x8*)&g_ws.W0t[gcb + m][q * 8];
            bf16x8 wa1 = *(const bf16x8*)&g_ws.W0t[gcb + m][32 + q * 8];
            f32x4 bias = *(const f32x4*)&g_ws.c0[gcb + q * 4];
            const int kg = w * 8 + nt * 2 + qh;
#pragma unroll
            for (int mt = 0; mt < 2; ++mt) {
                f32x4 c = {0.f, 0.f, 0.f, 0.f};
                c = mfma16(wa0, xrA[0][mt], c);
                c = mfma16(wa1, xrA[1][mt], c);
                u32x2 pw = { pk(fmaxf(c[1] + bias[1], 0.f), fmaxf(c[0] + bias[0], 0.f)),
                             pk(fmaxf(c[3] + bias[3], 0.f), fmaxf(c[2] + bias[2], 0.f)) };
                *(u32x2*)&sA[(kg * 32 + mt * 16 + m) * 8 + ql] = pw;
            }
        }
    }
    __syncthreads();   // B2

    // ---- P3: L1(A) || L0(B), fused loop (independent streams interleave) ----
    f32x4 acc1A[2][2];
#pragma unroll
    for (int a = 0; a < 2; ++a)
#pragma unroll
        for (int b = 0; b < 2; ++b) acc1A[a][b] = f32x4{0.f, 0.f, 0.f, 0.f};
    {
        bf16x8 xrB[2][2];
#pragma unroll
        for (int g2 = 0; g2 < 2; ++g2)
#pragma unroll
            for (int mt = 0; mt < 2; ++mt)
                xrB[g2][mt] = *(const bf16x8*)&sXs[((g2 * 4 + q) * 64 + 32 + mt * 16 + m) * 8];
#pragma unroll
        for (int ks = 0; ks < 16; ++ks) {
            bf16x8 wb[2], ab[2];
#pragma unroll
            for (int nt = 0; nt < 2; ++nt)
                wb[nt] = *(const bf16x8*)&g_ws.W1t[w * 32 + nt * 16 + m][ks * 32 + q * 8];
#pragma unroll
            for (int mt = 0; mt < 2; ++mt)
                ab[mt] = *(const bf16x8*)&sA[((ks * 4 + q) * 32 + mt * 16 + m) * 8];
#pragma unroll
            for (int nt = 0; nt < 2; ++nt)
#pragma unroll
                for (int mt = 0; mt < 2; ++mt)
                    acc1A[nt][mt] = mfma16(wb[nt], ab[mt], acc1A[nt][mt]);
            if ((ks & 3) == 0) {   // one L0(B) tile per 4 ks (reg-MFMA + ds_write)
                const int nt2 = ks >> 2;
                const int gcb = w * 64 + nt2 * 16;
                bf16x8 wa0 = *(const bf16x8*)&g_ws.W0t[gcb + m][q * 8];
                bf16x8 wa1 = *(const bf16x8*)&g_ws.W0t[gcb + m][32 + q * 8];
                f32x4 bias = *(const f32x4*)&g_ws.c0[gcb + q * 4];
                const int kg = w * 8 + nt2 * 2 + qh;
#pragma unroll
                for (int mt = 0; mt < 2; ++mt) {
                    f32x4 c = {0.f, 0.f, 0.f, 0.f};
                    c = mfma16(wa0, xrB[0][mt], c);
                    c = mfma16(wa1, xrB[1][mt], c);
                    u32x2 pw = { pk(fmaxf(c[1] + bias[1], 0.f), fmaxf(c[0] + bias[0], 0.f)),
                                 pk(fmaxf(c[3] + bias[3], 0.f), fmaxf(c[2] + bias[2], 0.f)) };
                    *(u32x2*)&sB[(kg * 32 + mt * 16 + m) * 8 + ql] = pw;
                }
            }
        }
    }
    __syncthreads();   // B3

    // ---- P4: H1(A)-write || L1(B) ----
#pragma unroll
    for (int nt = 0; nt < 2; ++nt) {
        const int cb = w * 32 + nt * 16;
        f32x4 bias = *(const f32x4*)&g_ws.c1[cb + q * 4];
        const int kg = w * 4 + nt * 2 + qh;
#pragma unroll
        for (int mt = 0; mt < 2; ++mt) {
            f32x4 c = acc1A[nt][mt];
            u32x2 pw = { pk(fmaxf(c[1] + bias[1], 0.f), fmaxf(c[0] + bias[0], 0.f)),
                         pk(fmaxf(c[3] + bias[3], 0.f), fmaxf(c[2] + bias[2], 0.f)) };
            *(u32x2*)&sA[(kg * 32 + mt * 16 + m) * 8 + ql] = pw;
        }
    }
    f32x4 acc1B[2][2];
#pragma unroll
    for (int a = 0; a < 2; ++a)
#pragma unroll
        for (int b = 0; b < 2; ++b) acc1B[a][b] = f32x4{0.f, 0.f, 0.f, 0.f};
#pragma unroll
    for (int ks = 0; ks < 16; ++ks) {
        bf16x8 wb[2], ab[2];
#pragma unroll
        for (int nt = 0; nt < 2; ++nt)
            wb[nt] = *(const bf16x8*)&g_ws.W1t[w * 32 + nt * 16 + m][ks * 32 + q * 8];
#pragma unroll
        for (int mt = 0; mt < 2; ++mt)
            ab[mt] = *(const bf16x8*)&sB[((ks * 4 + q) * 32 + mt * 16 + m) * 8];
#pragma unroll
        for (int nt = 0; nt < 2; ++nt)
#pragma unroll
            for (int mt = 0; mt < 2; ++mt)
                acc1B[nt][mt] = mfma16(wb[nt], ab[mt], acc1B[nt][mt]);
    }
    __syncthreads();   // B4

    // ---- P5: H1(B)-write || head1(A) ----
#pragma unroll
    for (int nt = 0; nt < 2; ++nt) {
        const int cb = w * 32 + nt * 16;
        f32x4 bias = *(const f32x4*)&g_ws.c1[cb + q * 4];
        const int kg = w * 4 + nt * 2 + qh;
#pragma unroll
        for (int mt = 0; mt < 2; ++mt) {
            f32x4 c = acc1B[nt][mt];
            u32x2 pw = { pk(fmaxf(c[1] + bias[1], 0.f), fmaxf(c[0] + bias[0], 0.f)),
                         pk(fmaxf(c[3] + bias[3], 0.f), fmaxf(c[2] + bias[2], 0.f)) };
            *(u32x2*)&sB[(kg * 32 + mt * 16 + m) * 8 + ql] = pw;
        }
    }
    const int cb1 = (w & 3) * 16;
    const unsigned short (*Wh)[256] = head ? g_ws.dW1t : g_ws.nW1t;
    const float* bh = head ? g_ws.db1c : g_ws.nb1c;
    f32x4 ahA[2];
    ahA[0] = f32x4{0.f, 0.f, 0.f, 0.f}; ahA[1] = f32x4{0.f, 0.f, 0.f, 0.f};
#pragma unroll
    for (int ks = 0; ks < 8; ++ks) {
        bf16x8 wh = *(const bf16x8*)&Wh[cb1 + m][ks * 32 + q * 8];
#pragma unroll
        for (int mt = 0; mt < 2; ++mt) {
            bf16x8 ab = *(const bf16x8*)&sA[((ks * 4 + q) * 32 + mt * 16 + m) * 8];
            ahA[mt] = mfma16(wh, ab, ahA[mt]);
        }
    }
    __syncthreads();   // B5

    // ---- P6: A(A)-write || head1(B) ----
    {
        unsigned short* AhA = sA + 8192 + head * 2048;   // A @ +16KB, 4KB/head
        f32x4 bias = *(const f32x4*)&bh[cb1 + q * 4];
        const int kg = (w & 3) * 2 + qh;
#pragma unroll
        for (int mt = 0; mt < 2; ++mt) {
            f32x4 c = ahA[mt];
            u32x2 pw = { pk(fmaxf(c[1] + bias[1], 0.f), fmaxf(c[0] + bias[0], 0.f)),
                         pk(fmaxf(c[3] + bias[3], 0.f), fmaxf(c[2] + bias[2], 0.f)) };
            *(u32x2*)&AhA[(kg * 32 + mt * 16 + m) * 8 + ql] = pw;
        }
    }
    f32x4 ahB[2];
    ahB[0] = f32x4{0.f, 0.f, 0.f, 0.f}; ahB[1] = f32x4{0.f, 0.f, 0.f, 0.f};
#pragma unroll
    for (int ks = 0; ks < 8; ++ks) {
        bf16x8 wh = *(const bf16x8*)&Wh[cb1 + m][ks * 32 + q * 8];
#pragma unroll
        for (int mt = 0; mt < 2; ++mt) {
            bf16x8 ab = *(const bf16x8*)&sB[((ks * 4 + q) * 32 + mt * 16 + m) * 8];
            ahB[mt] = mfma16(wh, ab, ahB[mt]);
        }
    }
    __syncthreads();   // B6

    // ---- head2 machinery (shared) ----
    const unsigned short (*W2)[64] = head ? g_ws.dW2t : g_ws.nW2t;
    const float* b2 = head ? g_ws.db2c : g_ws.nb2c;
    float* op = out + (size_t)head * (size_t)NB * 128;

    // ---- P7: A(B)-write || head2(A) ----
    {
        unsigned short* AhB = sB + 8192 + head * 2048;
        f32x4 bias = *(const f32x4*)&bh[cb1 + q * 4];
        const int kg = (w & 3) * 2 + qh;
#pragma unroll
        for (int mt = 0; mt < 2; ++mt) {
            f32x4 c = ahB[mt];
            u32x2 pw = { pk(fmaxf(c[1] + bias[1], 0.f), fmaxf(c[0] + bias[0], 0.f)),
                         pk(fmaxf(c[3] + bias[3], 0.f), fmaxf(c[2] + bias[2], 0.f)) };
            *(u32x2*)&AhB[(kg * 32 + mt * 16 + m) * 8 + ql] = pw;
        }
    }
    {
        const unsigned short* AhA = sA + 8192 + head * 2048;
        int thr[2];
#pragma unroll
        for (int mt = 0; mt < 2; ++mt) {
            unsigned tv = *(const unsigned*)&sXs[(7 * 64 + mt * 16 + m) * 8 + 4];
            thr[mt] = (int)__builtin_bit_cast(float, head ? (tv & 0xffff0000u) : (tv << 16));
        }
#pragma unroll
        for (int ct = 0; ct < 2; ++ct) {
            const int ocb = (w & 3) * 32 + ct * 16;
            bf16x8 w0 = *(const bf16x8*)&W2[ocb + m][q * 8];
            bf16x8 w1 = *(const bf16x8*)&W2[ocb + m][32 + q * 8];
            f32x4 bias = *(const f32x4*)&b2[ocb + q * 4];
#pragma unroll
            for (int mt = 0; mt < 2; ++mt) {
                bf16x8 a0 = *(const bf16x8*)&AhA[(q * 32 + mt * 16 + m) * 8];
                bf16x8 a1 = *(const bf16x8*)&AhA[((4 + q) * 32 + mt * 16 + m) * 8];
                f32x4 c = {0.f, 0.f, 0.f, 0.f};
                c = mfma16(w0, a0, c);
                c = mfma16(w1, a1, c);
                const int ci = ocb + q * 4;
                const int t = thr[mt];
                f32x4 v;
                v[0] = (ci + 0 <= t) ? c[0] + bias[0] : NEG9;
                v[1] = (ci + 1 <= t) ? c[1] + bias[1] : NEG9;
                v[2] = (ci + 2 <= t) ? c[2] + bias[2] : NEG9;
                v[3] = (ci + 3 <= t) ? c[3] + bias[3] : NEG9;
                *(f32x4*)&op[(size_t)(row0 + mt * 16 + m) * 128 + ci] = v;
            }
        }
    }
    __syncthreads();   // B7

    // ---- P8: head2(B) ----
    {
        const unsigned short* AhB = sB + 8192 + head * 2048;
        int thr[2];
#pragma unroll
        for (int mt = 0; mt < 2; ++mt) {
            unsigned tv = *(const unsigned*)&sXs[(7 * 64 + 32 + mt * 16 + m) * 8 + 4];
            thr[mt] = (int)__builtin_bit_cast(float, head ? (tv & 0xffff0000u) : (tv << 16));
        }
#pragma unroll
        for (int ct = 0; ct < 2; ++ct) {
            const int ocb = (w & 3) * 32 + ct * 16;
            bf16x8 w0 = *(const bf16x8*)&W2[ocb + m][q * 8];
            bf16x8 w1 = *(const bf16x8*)&W2[ocb + m][32 + q * 8];
            f32x4 bias = *(const f32x4*)&b2[ocb + q * 4];
#pragma unroll
            for (int mt = 0; mt < 2; ++mt) {
                bf16x8 a0 = *(const bf16x8*)&AhB[(q * 32 + mt * 16 + m) * 8];
                bf16x8 a1 = *(const bf16x8*)&AhB[((4 + q) * 32 + mt * 16 + m) * 8];
                f32x4 c = {0.f, 0.f, 0.f, 0.f};
                c = mfma16(w0, a0, c);
                c = mfma16(w1, a1, c);
                const int ci = ocb + q * 4;
                const int t = thr[mt];
                f32x4 v;
                v[0] = (ci + 0 <= t) ? c[0] + bias[0] : NEG9;
                v[1] = (ci + 1 <= t) ? c[1] + bias[1] : NEG9;
                v[2] = (ci + 2 <= t) ? c[2] + bias[2] : NEG9;
                v[3] = (ci + 3 <= t) ? c[3] + bias[3] : NEG9;
                *(f32x4*)&op[(size_t)(row0 + 32 + mt * 16 + m) * 128 + ci] = v;
            }
        }
    }
}

extern "C" void kernel_launch(void* const* d_in, const int* in_sizes, int n_in,
                              void* d_out, int out_size, void* d_ws, size_t ws_size,
                              hipStream_t stream) {
    (void)in_sizes; (void)n_in; (void)d_ws; (void)ws_size;

    prep_kernel<<<53, 256, 0, stream>>>(
        (const float*)d_in[1], (const float*)d_in[2], (const float*)d_in[3],
        (const float*)d_in[4], (const float*)d_in[5], (const float*)d_in[6],
        (const float*)d_in[7], (const float*)d_in[8], (const float*)d_in[9],
        (const float*)d_in[10], (const float*)d_in[11], (const float*)d_in[12],
        (const float*)d_in[13], (const float*)d_in[14], (const float*)d_in[15],
        (const float*)d_in[16], (const float*)d_in[17], (const float*)d_in[18],
        (const float*)d_in[19], (const float*)d_in[20]);

    fused_mlp<<<NB / 64, 512, 0, stream>>>((const u32x4*)d_in[0], (float*)d_out);
}

// Round 10
// 286.139 us; speedup vs baseline: 1.3356x; 1.3356x over previous
//
#include <hip/hip_runtime.h>

#define NB 131072
#define NEG9 -1e9f

typedef __attribute__((ext_vector_type(8))) __bf16 bf16x8;
typedef __attribute__((ext_vector_type(4))) float f32x4;
typedef __attribute__((ext_vector_type(2))) unsigned int u32x2;
typedef __attribute__((ext_vector_type(4))) unsigned int u32x4;

__device__ __forceinline__ f32x4 mfma16(bf16x8 a, bf16x8 b, f32x4 c) {
    return __builtin_amdgcn_mfma_f32_16x16x32_bf16(a, b, c, 0, 0, 0);
}

// pack two floats to bf16x2 (truncation) in ONE v_perm_b32: [hi16(h) | hi16(l)]
__device__ __forceinline__ unsigned pk(float h, float l) {
    return __builtin_amdgcn_perm(__builtin_bit_cast(unsigned, h),
                                 __builtin_bit_cast(unsigned, l), 0x07060302u);
}
__device__ __forceinline__ unsigned pku(unsigned h, unsigned l) {
    return __builtin_amdgcn_perm(h, l, 0x07060302u);
}

// float -> bf16 (RNE) for weight prep
__device__ __forceinline__ unsigned short f2bf(float f) {
    unsigned u = __builtin_bit_cast(unsigned, f);
    u += 0x7fffu + ((u >> 16) & 1u);
    return (unsigned short)(u >> 16);
}

// BN-folded, transposed (n-major, k-contiguous) bf16 weights + fp32 biases.
struct __align__(16) Wspace {
    unsigned short W0t[512][64];
    unsigned short W1t[256][512];
    unsigned short nW1t[64][256];
    unsigned short dW1t[64][256];
    unsigned short nW2t[128][64];
    unsigned short dW2t[128][64];
    float c0[512];
    float c1[256];
    float nb1c[64], db1c[64];
    float nb2c[128], db2c[128];
};

__device__ Wspace g_ws;

// r11 prep: 64x64 LDS-transpose tiles, fully coalesced both sides (kept).
__global__ __launch_bounds__(256) void prep_kernel(
    const float* __restrict__ W0, const float* __restrict__ b0,
    const float* __restrict__ g0, const float* __restrict__ be0,
    const float* __restrict__ rm0, const float* __restrict__ rv0,
    const float* __restrict__ W1, const float* __restrict__ b1,
    const float* __restrict__ g1, const float* __restrict__ be1,
    const float* __restrict__ rm1, const float* __restrict__ rv1,
    const float* __restrict__ nW1, const float* __restrict__ nb1,
    const float* __restrict__ nW2, const float* __restrict__ nb2,
    const float* __restrict__ dW1, const float* __restrict__ db1,
    const float* __restrict__ dW2, const float* __restrict__ db2)
{
    const int b = blockIdx.x;
    const int t = threadIdx.x;

    if (b == 52) {  // bias / BN-constant vectors (all coalesced)
        {   // c0[512]
            int i = t;          g_ws.c0[i] = (b0[i] - rm0[i]) * (g0[i] * rsqrtf(rv0[i] + 1e-5f)) + be0[i];
            i = t + 256;        g_ws.c0[i] = (b0[i] - rm0[i]) * (g0[i] * rsqrtf(rv0[i] + 1e-5f)) + be0[i];
        }
        g_ws.c1[t] = (b1[t] - rm1[t]) * (g1[t] * rsqrtf(rv1[t] + 1e-5f)) + be1[t];
        if (t < 64)  { g_ws.nb1c[t] = nb1[t]; g_ws.db1c[t] = db1[t]; }
        if (t < 128) { g_ws.nb2c[t] = nb2[t]; g_ws.db2c[t] = db2[t]; }
        return;
    }

    const float* src; unsigned short* dst;
    const float* gp = nullptr; const float* rvp = nullptr;
    int sld, dld, k0, n0;
    if (b < 32)      { src = W1;  dst = (unsigned short*)g_ws.W1t;  sld = 256; dld = 512;
                       k0 = (b >> 2) * 64; n0 = (b & 3) * 64; gp = g1; rvp = rv1; }
    else if (b < 40) { src = W0;  dst = (unsigned short*)g_ws.W0t;  sld = 512; dld = 64;
                       k0 = 0; n0 = (b - 32) * 64; gp = g0; rvp = rv0; }
    else if (b < 44) { src = nW1; dst = (unsigned short*)g_ws.nW1t; sld = 64;  dld = 256;
                       k0 = (b - 40) * 64; n0 = 0; }
    else if (b < 48) { src = dW1; dst = (unsigned short*)g_ws.dW1t; sld = 64;  dld = 256;
                       k0 = (b - 44) * 64; n0 = 0; }
    else if (b < 50) { src = nW2; dst = (unsigned short*)g_ws.nW2t; sld = 128; dld = 64;
                       k0 = 0; n0 = (b - 48) * 64; }
    else             { src = dW2; dst = (unsigned short*)g_ws.dW2t; sld = 128; dld = 64;
                       k0 = 0; n0 = (b - 50) * 64; }

    __shared__ unsigned short tile[64][66];

    const int rr = t >> 4;
    const int cc = (t & 15) * 4;

#pragma unroll
    for (int g = 0; g < 4; ++g) {
        const int r = rr + g * 16;
        f32x4 v = *(const f32x4*)&src[(size_t)(k0 + r) * sld + n0 + cc];
        if (gp) {
            f32x4 gv = *(const f32x4*)&gp[n0 + cc];
            f32x4 rv = *(const f32x4*)&rvp[n0 + cc];
            v[0] *= gv[0] * rsqrtf(rv[0] + 1e-5f);
            v[1] *= gv[1] * rsqrtf(rv[1] + 1e-5f);
            v[2] *= gv[2] * rsqrtf(rv[2] + 1e-5f);
            v[3] *= gv[3] * rsqrtf(rv[3] + 1e-5f);
        }
        *(unsigned*)&tile[r][cc]     = (unsigned)f2bf(v[0]) | ((unsigned)f2bf(v[1]) << 16);
        *(unsigned*)&tile[r][cc + 2] = (unsigned)f2bf(v[2]) | ((unsigned)f2bf(v[3]) << 16);
    }
    __syncthreads();

#pragma unroll
    for (int g = 0; g < 4; ++g) {
        const int n = rr + g * 16;
        unsigned o01 = (unsigned)tile[cc + 0][n] | ((unsigned)tile[cc + 1][n] << 16);
        unsigned o23 = (unsigned)tile[cc + 2][n] | ((unsigned)tile[cc + 3][n] << 16);
        u32x2 o = { o01, o23 };
        *(u32x2*)&dst[(size_t)(n0 + n) * dld + k0 + cc] = o;
    }
}

// LEDGER: fused ~135us robust vs occupancy(44/58/78%), LDS(40-73KB), LDS
//   traffic(-40%), barriers(8->6: -3%), ILP/4-wave(r12: 146), two-stream
//   skew(r13: 232, compiler kept streams sequential). Sequential-sum of
//   pipes (~280k cyc) ~= wall (324k) -> structural phase serialization;
//   wave-independent variant ruled out by arithmetic (4x L2 weight traffic
//   = 107us alone). Best verified: r11 (bench 285.8, fused 134.5).
// r14: r11 EXACT revert + ONE change: An/Ad moved to sH0 granules 32..47
//   (dead H0 region after B3) instead of overlaying H1 -> overlay hazard
//   gone -> B5 deleted. Barriers 6 -> 5. Everything else byte-identical.
__global__ __launch_bounds__(512, 4) void fused_mlp(
    const u32x4* __restrict__ xu, float* __restrict__ out)
{
    __shared__ __align__(16) unsigned short sXs[8 * 64 * 8];    //  8 KB (X, live to end)
    __shared__ __align__(16) unsigned short sH0[64 * 64 * 8];   // 64 KB (H0 full / H1 + A)

    const int tid = threadIdx.x;
    const int w = tid >> 6;          // wave 0..7
    const int lane = tid & 63;
    const int m = lane & 15;
    const int q = lane >> 4;
    const int qh = q >> 1;
    const int ql = (q & 1) * 4;
    const int row0 = blockIdx.x * 64;

    // ---- stage X -> bf16 granule-major [g][r][8] (one row-granule/thread) ----
    {
        int r = tid >> 3, g = tid & 7;
        u32x4 v0 = __builtin_nontemporal_load(&xu[(size_t)(row0 + r) * 16 + g * 2]);
        u32x4 v1 = __builtin_nontemporal_load(&xu[(size_t)(row0 + r) * 16 + g * 2 + 1]);
        u32x4 p = { pku(v0[1], v0[0]), pku(v0[3], v0[2]), pku(v1[1], v1[0]), pku(v1[3], v1[2]) };
        *(u32x4*)&sXs[(g * 64 + r) * 8] = p;
    }
    __syncthreads();   // B1

    // ---- hoist X fragments into registers: 8 x bf16x8 = 32 VGPR, read ONCE ----
    bf16x8 xr[2][4];
#pragma unroll
    for (int g2 = 0; g2 < 2; ++g2)
#pragma unroll
        for (int mt = 0; mt < 4; ++mt)
            xr[g2][mt] = *(const bf16x8*)&sXs[((g2 * 4 + q) * 64 + mt * 16 + m) * 8];

    // ---- layer0: FULL 512 cols in one phase; wave w -> cols [w*64, +64) ----
#pragma unroll
    for (int nt = 0; nt < 4; ++nt) {
        const int gcb = w * 64 + nt * 16;
        bf16x8 wa0 = *(const bf16x8*)&g_ws.W0t[gcb + m][q * 8];
        bf16x8 wa1 = *(const bf16x8*)&g_ws.W0t[gcb + m][32 + q * 8];
        f32x4 bias = *(const f32x4*)&g_ws.c0[gcb + q * 4];
        const int kg = w * 8 + nt * 2 + qh;    // granule 0..63
#pragma unroll
        for (int mt = 0; mt < 4; ++mt) {
            f32x4 c = {0.f, 0.f, 0.f, 0.f};
            c = mfma16(wa0, xr[0][mt], c);
            c = mfma16(wa1, xr[1][mt], c);
            u32x2 pw = { pk(fmaxf(c[1] + bias[1], 0.f), fmaxf(c[0] + bias[0], 0.f)),
                         pk(fmaxf(c[3] + bias[3], 0.f), fmaxf(c[2] + bias[2], 0.f)) };
            *(u32x2*)&sH0[(kg * 64 + mt * 16 + m) * 8 + ql] = pw;
        }
    }
    __syncthreads();   // B2

    // ---- layer1: K=512 in ONE phase, 16 ks of independent load+MFMA ----
    f32x4 acc1[2][4];
#pragma unroll
    for (int a = 0; a < 2; ++a)
#pragma unroll
        for (int b = 0; b < 4; ++b) acc1[a][b] = f32x4{0.f, 0.f, 0.f, 0.f};

#pragma unroll
    for (int ks = 0; ks < 16; ++ks) {
        bf16x8 wb[2], ab[4];
#pragma unroll
        for (int nt = 0; nt < 2; ++nt)
            wb[nt] = *(const bf16x8*)&g_ws.W1t[w * 32 + nt * 16 + m][ks * 32 + q * 8];
#pragma unroll
        for (int mt = 0; mt < 4; ++mt)
            ab[mt] = *(const bf16x8*)&sH0[((ks * 4 + q) * 64 + mt * 16 + m) * 8];
#pragma unroll
        for (int nt = 0; nt < 2; ++nt)
#pragma unroll
            for (int mt = 0; mt < 4; ++mt)
                acc1[nt][mt] = mfma16(wb[nt], ab[mt], acc1[nt][mt]);
    }
    __syncthreads();   // B3 (all H0 reads done; H1 may overlay granules 0..31)

    // ---- H1 = relu(acc1 + c1) -> sH0 granules [0,32) (H0 region dead) ----
#pragma unroll
    for (int nt = 0; nt < 2; ++nt) {
        const int cb = w * 32 + nt * 16;
        f32x4 bias = *(const f32x4*)&g_ws.c1[cb + q * 4];
        const int kg = w * 4 + nt * 2 + qh;    // granule 0..31
#pragma unroll
        for (int mt = 0; mt < 4; ++mt) {
            f32x4 c = acc1[nt][mt];
            u32x2 pw = { pk(fmaxf(c[1] + bias[1], 0.f), fmaxf(c[0] + bias[0], 0.f)),
                         pk(fmaxf(c[3] + bias[3], 0.f), fmaxf(c[2] + bias[2], 0.f)) };
            *(u32x2*)&sH0[(kg * 64 + mt * 16 + m) * 8 + ql] = pw;
        }
    }
    __syncthreads();   // B4

    // ---- head layer 1: head = w>>2, cols (w&3)*16..+16, K=256 ----
    // A lands in granules 32..47 (dead since B3) -> NO overlay with H1 ->
    // no barrier needed between head1's H1-reads and the A-write (r14).
    const int head = w >> 2;
    {
        const int cb = (w & 3) * 16;
        const unsigned short (*Wh)[256] = head ? g_ws.dW1t : g_ws.nW1t;
        const float* bh = head ? g_ws.db1c : g_ws.nb1c;
        f32x4 acc[4];
#pragma unroll
        for (int b = 0; b < 4; ++b) acc[b] = f32x4{0.f, 0.f, 0.f, 0.f};
#pragma unroll
        for (int ks = 0; ks < 8; ++ks) {
            bf16x8 wh = *(const bf16x8*)&Wh[cb + m][ks * 32 + q * 8];
#pragma unroll
            for (int mt = 0; mt < 4; ++mt) {
                bf16x8 ab = *(const bf16x8*)&sH0[((ks * 4 + q) * 64 + mt * 16 + m) * 8];
                acc[mt] = mfma16(wh, ab, acc[mt]);
            }
        }
        unsigned short* Ah = sH0 + 16384 + head * 4096;  // An @ gran 32, Ad @ gran 40
        f32x4 bias = *(const f32x4*)&bh[cb + q * 4];
        const int kg = (w & 3) * 2 + qh;
#pragma unroll
        for (int mt = 0; mt < 4; ++mt) {
            f32x4 c = acc[mt];
            u32x2 pw = { pk(fmaxf(c[1] + bias[1], 0.f), fmaxf(c[0] + bias[0], 0.f)),
                         pk(fmaxf(c[3] + bias[3], 0.f), fmaxf(c[2] + bias[2], 0.f)) };
            *(u32x2*)&Ah[(kg * 64 + mt * 16 + m) * 8 + ql] = pw;
        }
    }
    __syncthreads();   // B5' (A fully written before head2 reads it)

    // ---- head layer 2 + mask + plain dwordx4 stores ----
    {
        const unsigned short (*W2)[64] = head ? g_ws.dW2t : g_ws.nW2t;
        const float* b2 = head ? g_ws.db2c : g_ws.nb2c;
        const unsigned short* Ah = sH0 + 16384 + head * 4096;
        float* op = out + (size_t)head * (size_t)NB * 128;

        // thresholds via r4's PROVEN sXs path: granule 7 elems 4,5 = cols 60,61
        // (class ids 0..127 exact in bf16); sXs untouched throughout
        int thr[4];
#pragma unroll
        for (int mt = 0; mt < 4; ++mt) {
            unsigned tv = *(const unsigned*)&sXs[(7 * 64 + mt * 16 + m) * 8 + 4];
            thr[mt] = (int)__builtin_bit_cast(float, head ? (tv & 0xffff0000u) : (tv << 16));
        }
#pragma unroll
        for (int ct = 0; ct < 2; ++ct) {
            const int ocb = (w & 3) * 32 + ct * 16;
            bf16x8 w0 = *(const bf16x8*)&W2[ocb + m][q * 8];
            bf16x8 w1 = *(const bf16x8*)&W2[ocb + m][32 + q * 8];
            f32x4 bias = *(const f32x4*)&b2[ocb + q * 4];
#pragma unroll
            for (int mt = 0; mt < 4; ++mt) {
                bf16x8 a0 = *(const bf16x8*)&Ah[(q * 64 + mt * 16 + m) * 8];
                bf16x8 a1 = *(const bf16x8*)&Ah[((4 + q) * 64 + mt * 16 + m) * 8];
                f32x4 c = {0.f, 0.f, 0.f, 0.f};
                c = mfma16(w0, a0, c);
                c = mfma16(w1, a1, c);
                const int ci = ocb + q * 4;
                const int t = thr[mt];
                f32x4 v;
                v[0] = (ci + 0 <= t) ? c[0] + bias[0] : NEG9;
                v[1] = (ci + 1 <= t) ? c[1] + bias[1] : NEG9;
                v[2] = (ci + 2 <= t) ? c[2] + bias[2] : NEG9;
                v[3] = (ci + 3 <= t) ? c[3] + bias[3] : NEG9;
                *(f32x4*)&op[(size_t)(row0 + mt * 16 + m) * 128 + ci] = v;
            }
        }
    }
}

extern "C" void kernel_launch(void* const* d_in, const int* in_sizes, int n_in,
                              void* d_out, int out_size, void* d_ws, size_t ws_size,
                              hipStream_t stream) {
    (void)in_sizes; (void)n_in; (void)d_ws; (void)ws_size;

    prep_kernel<<<53, 256, 0, stream>>>(
        (const float*)d_in[1], (const float*)d_in[2], (const float*)d_in[3],
        (const float*)d_in[4], (const float*)d_in[5], (const float*)d_in[6],
        (const float*)d_in[7], (const float*)d_in[8], (const float*)d_in[9],
        (const float*)d_in[10], (const float*)d_in[11], (const float*)d_in[12],
        (const float*)d_in[13], (const float*)d_in[14], (const float*)d_in[15],
        (const float*)d_in[16], (const float*)d_in[17], (const float*)d_in[18],
        (const float*)d_in[19], (const float*)d_in[20]);

    fused_mlp<<<NB / 64, 512, 0, stream>>>((const u32x4*)d_in[0], (float*)d_out);
}

// Round 11
// 275.127 us; speedup vs baseline: 1.3890x; 1.0400x over previous
//
#include <hip/hip_runtime.h>

#define NB 131072
#define NEG9 -1e9f

typedef __attribute__((ext_vector_type(8))) __bf16 bf16x8;
typedef __attribute__((ext_vector_type(4))) float f32x4;
typedef __attribute__((ext_vector_type(2))) unsigned int u32x2;
typedef __attribute__((ext_vector_type(4))) unsigned int u32x4;

__device__ __forceinline__ f32x4 mfma16(bf16x8 a, bf16x8 b, f32x4 c) {
    return __builtin_amdgcn_mfma_f32_16x16x32_bf16(a, b, c, 0, 0, 0);
}

// pack two floats to bf16x2 (truncation) in ONE v_perm_b32: [hi16(h) | hi16(l)]
__device__ __forceinline__ unsigned pk(float h, float l) {
    return __builtin_amdgcn_perm(__builtin_bit_cast(unsigned, h),
                                 __builtin_bit_cast(unsigned, l), 0x07060302u);
}
__device__ __forceinline__ unsigned pku(unsigned h, unsigned l) {
    return __builtin_amdgcn_perm(h, l, 0x07060302u);
}

// float -> bf16 (RNE) for weight prep
__device__ __forceinline__ unsigned short f2bf(float f) {
    unsigned u = __builtin_bit_cast(unsigned, f);
    u += 0x7fffu + ((u >> 16) & 1u);
    return (unsigned short)(u >> 16);
}

// BN-folded, transposed (n-major, k-contiguous) bf16 weights + fp32 biases.
struct __align__(16) Wspace {
    unsigned short W0t[512][64];
    unsigned short W1t[256][512];
    unsigned short nW1t[64][256];
    unsigned short dW1t[64][256];
    unsigned short nW2t[128][64];
    unsigned short dW2t[128][64];
    float c0[512];
    float c1[256];
    float nb1c[64], db1c[64];
    float nb2c[128], db2c[128];
};

__device__ Wspace g_ws;

// r11 prep: 64x64 LDS-transpose tiles, fully coalesced both sides (kept).
__global__ __launch_bounds__(256) void prep_kernel(
    const float* __restrict__ W0, const float* __restrict__ b0,
    const float* __restrict__ g0, const float* __restrict__ be0,
    const float* __restrict__ rm0, const float* __restrict__ rv0,
    const float* __restrict__ W1, const float* __restrict__ b1,
    const float* __restrict__ g1, const float* __restrict__ be1,
    const float* __restrict__ rm1, const float* __restrict__ rv1,
    const float* __restrict__ nW1, const float* __restrict__ nb1,
    const float* __restrict__ nW2, const float* __restrict__ nb2,
    const float* __restrict__ dW1, const float* __restrict__ db1,
    const float* __restrict__ dW2, const float* __restrict__ db2)
{
    const int b = blockIdx.x;
    const int t = threadIdx.x;

    if (b == 52) {  // bias / BN-constant vectors (all coalesced)
        {   // c0[512]
            int i = t;          g_ws.c0[i] = (b0[i] - rm0[i]) * (g0[i] * rsqrtf(rv0[i] + 1e-5f)) + be0[i];
            i = t + 256;        g_ws.c0[i] = (b0[i] - rm0[i]) * (g0[i] * rsqrtf(rv0[i] + 1e-5f)) + be0[i];
        }
        g_ws.c1[t] = (b1[t] - rm1[t]) * (g1[t] * rsqrtf(rv1[t] + 1e-5f)) + be1[t];
        if (t < 64)  { g_ws.nb1c[t] = nb1[t]; g_ws.db1c[t] = db1[t]; }
        if (t < 128) { g_ws.nb2c[t] = nb2[t]; g_ws.db2c[t] = db2[t]; }
        return;
    }

    const float* src; unsigned short* dst;
    const float* gp = nullptr; const float* rvp = nullptr;
    int sld, dld, k0, n0;
    if (b < 32)      { src = W1;  dst = (unsigned short*)g_ws.W1t;  sld = 256; dld = 512;
                       k0 = (b >> 2) * 64; n0 = (b & 3) * 64; gp = g1; rvp = rv1; }
    else if (b < 40) { src = W0;  dst = (unsigned short*)g_ws.W0t;  sld = 512; dld = 64;
                       k0 = 0; n0 = (b - 32) * 64; gp = g0; rvp = rv0; }
    else if (b < 44) { src = nW1; dst = (unsigned short*)g_ws.nW1t; sld = 64;  dld = 256;
                       k0 = (b - 40) * 64; n0 = 0; }
    else if (b < 48) { src = dW1; dst = (unsigned short*)g_ws.dW1t; sld = 64;  dld = 256;
                       k0 = (b - 44) * 64; n0 = 0; }
    else if (b < 50) { src = nW2; dst = (unsigned short*)g_ws.nW2t; sld = 128; dld = 64;
                       k0 = 0; n0 = (b - 48) * 64; }
    else             { src = dW2; dst = (unsigned short*)g_ws.dW2t; sld = 128; dld = 64;
                       k0 = 0; n0 = (b - 50) * 64; }

    __shared__ unsigned short tile[64][66];

    const int rr = t >> 4;
    const int cc = (t & 15) * 4;

#pragma unroll
    for (int g = 0; g < 4; ++g) {
        const int r = rr + g * 16;
        f32x4 v = *(const f32x4*)&src[(size_t)(k0 + r) * sld + n0 + cc];
        if (gp) {
            f32x4 gv = *(const f32x4*)&gp[n0 + cc];
            f32x4 rv = *(const f32x4*)&rvp[n0 + cc];
            v[0] *= gv[0] * rsqrtf(rv[0] + 1e-5f);
            v[1] *= gv[1] * rsqrtf(rv[1] + 1e-5f);
            v[2] *= gv[2] * rsqrtf(rv[2] + 1e-5f);
            v[3] *= gv[3] * rsqrtf(rv[3] + 1e-5f);
        }
        *(unsigned*)&tile[r][cc]     = (unsigned)f2bf(v[0]) | ((unsigned)f2bf(v[1]) << 16);
        *(unsigned*)&tile[r][cc + 2] = (unsigned)f2bf(v[2]) | ((unsigned)f2bf(v[3]) << 16);
    }
    __syncthreads();

#pragma unroll
    for (int g = 0; g < 4; ++g) {
        const int n = rr + g * 16;
        unsigned o01 = (unsigned)tile[cc + 0][n] | ((unsigned)tile[cc + 1][n] << 16);
        unsigned o23 = (unsigned)tile[cc + 2][n] | ((unsigned)tile[cc + 3][n] << 16);
        u32x2 o = { o01, o23 };
        *(u32x2*)&dst[(size_t)(n0 + n) * dld + k0 + cc] = o;
    }
}

// LEDGER: fused ~134us robust vs occupancy(22-78%), regs(60-108), LDS
//   (40-73KB), LDS traffic(-40%), barriers(8->6->5), ILP(r12:146), stream
//   skew(r13:232). Only fatter phases ever helped (r10: -3%).
// r15: AMORTIZE THE SKELETON OVER 2x ROWS. 1024 blocks x 128 rows: per-row
//   barriers halve (8/128 vs 5/64=10/128) and per-row L2 weight traffic
//   halves (every block still reads all 425KB of weights; blocks halve:
//   870->435MB total, L2-wait ~19% of wall -> ~9% saving expected).
//   Structure: X 16KB; H0 K-chunked 2x256 (chunk 64KB, r6 scheme at row-
//   stride 128); H1 64KB overlays chunk region; An/Ad 32KB overlay H1 behind
//   extra barrier (r5 scheme). LDS 81920 -> 2 blocks/CU. acc1[2][8]=64 VGPR.
//   Spill tripwire: WRITE > 145MB -> revert to r14.
__global__ __launch_bounds__(512, 4) void fused_mlp(
    const u32x4* __restrict__ xu, float* __restrict__ out)
{
    __shared__ __align__(16) unsigned short sXs[8 * 128 * 8];   // 16 KB (X, live to end)
    __shared__ __align__(16) unsigned short sH[32 * 128 * 8];   // 64 KB (H0 chunk / H1 / A)

    const int tid = threadIdx.x;
    const int w = tid >> 6;          // wave 0..7
    const int lane = tid & 63;
    const int m = lane & 15;
    const int q = lane >> 4;
    const int qh = q >> 1;
    const int ql = (q & 1) * 4;
    const int row0 = blockIdx.x * 128;

    // ---- stage X -> bf16 granule-major [g][r][8]; 2 units/thread ----
    {
        int r = tid >> 3, g = tid & 7;
#pragma unroll
        for (int hh = 0; hh < 2; ++hh) {
            int rr = r + hh * 64;
            u32x4 v0 = __builtin_nontemporal_load(&xu[(size_t)(row0 + rr) * 16 + g * 2]);
            u32x4 v1 = __builtin_nontemporal_load(&xu[(size_t)(row0 + rr) * 16 + g * 2 + 1]);
            u32x4 p = { pku(v0[1], v0[0]), pku(v0[3], v0[2]), pku(v1[1], v1[0]), pku(v1[3], v1[2]) };
            *(u32x4*)&sXs[(g * 128 + rr) * 8] = p;
        }
    }
    __syncthreads();   // B1

    // ---- layers 0+1, 2 K-chunks of 256; layer-1 partials in regs ----
    f32x4 acc1[2][8];
#pragma unroll
    for (int a = 0; a < 2; ++a)
#pragma unroll
        for (int b = 0; b < 8; ++b) acc1[a][b] = f32x4{0.f, 0.f, 0.f, 0.f};

    for (int ch = 0; ch < 2; ++ch) {
        // layer0: wave w -> chunk cols [w*32,+32), 128 rows
#pragma unroll
        for (int nt = 0; nt < 2; ++nt) {
            const int gcb = ch * 256 + w * 32 + nt * 16;
            bf16x8 wa0 = *(const bf16x8*)&g_ws.W0t[gcb + m][q * 8];
            bf16x8 wa1 = *(const bf16x8*)&g_ws.W0t[gcb + m][32 + q * 8];
            f32x4 bias = *(const f32x4*)&g_ws.c0[gcb + q * 4];
            const int kg = w * 4 + nt * 2 + qh;    // granule 0..31
#pragma unroll
            for (int mt = 0; mt < 8; ++mt) {
                bf16x8 xq0 = *(const bf16x8*)&sXs[(q * 128 + mt * 16 + m) * 8];
                bf16x8 xq1 = *(const bf16x8*)&sXs[((4 + q) * 128 + mt * 16 + m) * 8];
                f32x4 c = {0.f, 0.f, 0.f, 0.f};
                c = mfma16(wa0, xq0, c);
                c = mfma16(wa1, xq1, c);
                u32x2 pw = { pk(fmaxf(c[1] + bias[1], 0.f), fmaxf(c[0] + bias[0], 0.f)),
                             pk(fmaxf(c[3] + bias[3], 0.f), fmaxf(c[2] + bias[2], 0.f)) };
                *(u32x2*)&sH[(kg * 128 + mt * 16 + m) * 8 + ql] = pw;
            }
        }
        __syncthreads();   // B2 / B4

        // layer1 partial: wave w -> out cols [w*32,+32), K-chunk 256
#pragma unroll
        for (int ks = 0; ks < 8; ++ks) {
            bf16x8 wb[2], ab[8];
#pragma unroll
            for (int nt = 0; nt < 2; ++nt)
                wb[nt] = *(const bf16x8*)&g_ws.W1t[w * 32 + nt * 16 + m][ch * 256 + ks * 32 + q * 8];
#pragma unroll
            for (int mt = 0; mt < 8; ++mt)
                ab[mt] = *(const bf16x8*)&sH[((ks * 4 + q) * 128 + mt * 16 + m) * 8];
#pragma unroll
            for (int nt = 0; nt < 2; ++nt)
#pragma unroll
                for (int mt = 0; mt < 8; ++mt)
                    acc1[nt][mt] = mfma16(wb[nt], ab[mt], acc1[nt][mt]);
        }
        __syncthreads();   // B3 / B5
    }

    // ---- H1 = relu(acc1 + c1) -> sH (whole chunk region dead after B5) ----
#pragma unroll
    for (int nt = 0; nt < 2; ++nt) {
        const int cb = w * 32 + nt * 16;
        f32x4 bias = *(const f32x4*)&g_ws.c1[cb + q * 4];
        const int kg = w * 4 + nt * 2 + qh;    // granule 0..31
#pragma unroll
        for (int mt = 0; mt < 8; ++mt) {
            f32x4 c = acc1[nt][mt];
            u32x2 pw = { pk(fmaxf(c[1] + bias[1], 0.f), fmaxf(c[0] + bias[0], 0.f)),
                         pk(fmaxf(c[3] + bias[3], 0.f), fmaxf(c[2] + bias[2], 0.f)) };
            *(u32x2*)&sH[(kg * 128 + mt * 16 + m) * 8 + ql] = pw;
        }
    }
    __syncthreads();   // B6

    // ---- head layer 1: head = w>>2, cols (w&3)*16..+16, K=256, 128 rows ----
    const int head = w >> 2;
    {
        const int cb = (w & 3) * 16;
        const unsigned short (*Wh)[256] = head ? g_ws.dW1t : g_ws.nW1t;
        const float* bh = head ? g_ws.db1c : g_ws.nb1c;
        f32x4 acc[8];
#pragma unroll
        for (int b = 0; b < 8; ++b) acc[b] = f32x4{0.f, 0.f, 0.f, 0.f};
#pragma unroll
        for (int ks = 0; ks < 8; ++ks) {
            bf16x8 wh = *(const bf16x8*)&Wh[cb + m][ks * 32 + q * 8];
#pragma unroll
            for (int mt = 0; mt < 8; ++mt) {
                bf16x8 ab = *(const bf16x8*)&sH[((ks * 4 + q) * 128 + mt * 16 + m) * 8];
                acc[mt] = mfma16(wh, ab, acc[mt]);
            }
        }
        // all waves' H1 reads must finish before A overlays sH
        __syncthreads();   // B7
        unsigned short* Ah = sH + head * 8192;   // An @ [0,16KB), Ad @ [16KB,32KB)
        f32x4 bias = *(const f32x4*)&bh[cb + q * 4];
        const int kg = (w & 3) * 2 + qh;         // granule 0..7 within head's A
#pragma unroll
        for (int mt = 0; mt < 8; ++mt) {
            f32x4 c = acc[mt];
            u32x2 pw = { pk(fmaxf(c[1] + bias[1], 0.f), fmaxf(c[0] + bias[0], 0.f)),
                         pk(fmaxf(c[3] + bias[3], 0.f), fmaxf(c[2] + bias[2], 0.f)) };
            *(u32x2*)&Ah[(kg * 128 + mt * 16 + m) * 8 + ql] = pw;
        }
    }
    __syncthreads();   // B8

    // ---- head layer 2 + mask + plain dwordx4 stores ----
    {
        const unsigned short (*W2)[64] = head ? g_ws.dW2t : g_ws.nW2t;
        const float* b2 = head ? g_ws.db2c : g_ws.nb2c;
        const unsigned short* Ah = sH + head * 8192;
        float* op = out + (size_t)head * (size_t)NB * 128;

        // thresholds via PROVEN sXs path: granule 7 elems 4,5 = cols 60,61
        // (class ids 0..127 exact in bf16); sXs untouched throughout
        int thr[8];
#pragma unroll
        for (int mt = 0; mt < 8; ++mt) {
            unsigned tv = *(const unsigned*)&sXs[(7 * 128 + mt * 16 + m) * 8 + 4];
            thr[mt] = (int)__builtin_bit_cast(float, head ? (tv & 0xffff0000u) : (tv << 16));
        }
#pragma unroll
        for (int ct = 0; ct < 2; ++ct) {
            const int ocb = (w & 3) * 32 + ct * 16;
            bf16x8 w0 = *(const bf16x8*)&W2[ocb + m][q * 8];
            bf16x8 w1 = *(const bf16x8*)&W2[ocb + m][32 + q * 8];
            f32x4 bias = *(const f32x4*)&b2[ocb + q * 4];
#pragma unroll
            for (int mt = 0; mt < 8; ++mt) {
                bf16x8 a0 = *(const bf16x8*)&Ah[(q * 128 + mt * 16 + m) * 8];
                bf16x8 a1 = *(const bf16x8*)&Ah[((4 + q) * 128 + mt * 16 + m) * 8];
                f32x4 c = {0.f, 0.f, 0.f, 0.f};
                c = mfma16(w0, a0, c);
                c = mfma16(w1, a1, c);
                const int ci = ocb + q * 4;
                const int t = thr[mt];
                f32x4 v;
                v[0] = (ci + 0 <= t) ? c[0] + bias[0] : NEG9;
                v[1] = (ci + 1 <= t) ? c[1] + bias[1] : NEG9;
                v[2] = (ci + 2 <= t) ? c[2] + bias[2] : NEG9;
                v[3] = (ci + 3 <= t) ? c[3] + bias[3] : NEG9;
                *(f32x4*)&op[(size_t)(row0 + mt * 16 + m) * 128 + ci] = v;
            }
        }
    }
}

extern "C" void kernel_launch(void* const* d_in, const int* in_sizes, int n_in,
                              void* d_out, int out_size, void* d_ws, size_t ws_size,
                              hipStream_t stream) {
    (void)in_sizes; (void)n_in; (void)d_ws; (void)ws_size;

    prep_kernel<<<53, 256, 0, stream>>>(
        (const float*)d_in[1], (const float*)d_in[2], (const float*)d_in[3],
        (const float*)d_in[4], (const float*)d_in[5], (const float*)d_in[6],
        (const float*)d_in[7], (const float*)d_in[8], (const float*)d_in[9],
        (const float*)d_in[10], (const float*)d_in[11], (const float*)d_in[12],
        (const float*)d_in[13], (const float*)d_in[14], (const float*)d_in[15],
        (const float*)d_in[16], (const float*)d_in[17], (const float*)d_in[18],
        (const float*)d_in[19], (const float*)d_in[20]);

    fused_mlp<<<NB / 128, 512, 0, stream>>>((const u32x4*)d_in[0], (float*)d_out);
}

// Round 12
// 255.921 us; speedup vs baseline: 1.4933x; 1.0750x over previous
//
#include <hip/hip_runtime.h>

#define NB 131072
#define NEG9 -1e9f

typedef __attribute__((ext_vector_type(8))) __bf16 bf16x8;
typedef __attribute__((ext_vector_type(4))) float f32x4;
typedef __attribute__((ext_vector_type(2))) unsigned int u32x2;
typedef __attribute__((ext_vector_type(4))) unsigned int u32x4;

__device__ __forceinline__ f32x4 mfma16(bf16x8 a, bf16x8 b, f32x4 c) {
    return __builtin_amdgcn_mfma_f32_16x16x32_bf16(a, b, c, 0, 0, 0);
}

// pack two floats to bf16x2 (truncation) in ONE v_perm_b32: [hi16(h) | hi16(l)]
__device__ __forceinline__ unsigned pk(float h, float l) {
    return __builtin_amdgcn_perm(__builtin_bit_cast(unsigned, h),
                                 __builtin_bit_cast(unsigned, l), 0x07060302u);
}
__device__ __forceinline__ unsigned pku(unsigned h, unsigned l) {
    return __builtin_amdgcn_perm(h, l, 0x07060302u);
}

// float -> bf16 (RNE) for weight prep
__device__ __forceinline__ unsigned short f2bf(float f) {
    unsigned u = __builtin_bit_cast(unsigned, f);
    u += 0x7fffu + ((u >> 16) & 1u);
    return (unsigned short)(u >> 16);
}

// BN-folded, transposed (n-major, k-contiguous) bf16 weights + fp32 biases.
struct __align__(16) Wspace {
    unsigned short W0t[512][64];
    unsigned short W1t[256][512];
    unsigned short nW1t[64][256];
    unsigned short dW1t[64][256];
    unsigned short nW2t[128][64];
    unsigned short dW2t[128][64];
    float c0[512];
    float c1[256];
    float nb1c[64], db1c[64];
    float nb2c[128], db2c[128];
};

__device__ Wspace g_ws;

// r11 prep: 64x64 LDS-transpose tiles, fully coalesced both sides (kept).
__global__ __launch_bounds__(256) void prep_kernel(
    const float* __restrict__ W0, const float* __restrict__ b0,
    const float* __restrict__ g0, const float* __restrict__ be0,
    const float* __restrict__ rm0, const float* __restrict__ rv0,
    const float* __restrict__ W1, const float* __restrict__ b1,
    const float* __restrict__ g1, const float* __restrict__ be1,
    const float* __restrict__ rm1, const float* __restrict__ rv1,
    const float* __restrict__ nW1, const float* __restrict__ nb1,
    const float* __restrict__ nW2, const float* __restrict__ nb2,
    const float* __restrict__ dW1, const float* __restrict__ db1,
    const float* __restrict__ dW2, const float* __restrict__ db2)
{
    const int b = blockIdx.x;
    const int t = threadIdx.x;

    if (b == 52) {  // bias / BN-constant vectors (all coalesced)
        {   // c0[512]
            int i = t;          g_ws.c0[i] = (b0[i] - rm0[i]) * (g0[i] * rsqrtf(rv0[i] + 1e-5f)) + be0[i];
            i = t + 256;        g_ws.c0[i] = (b0[i] - rm0[i]) * (g0[i] * rsqrtf(rv0[i] + 1e-5f)) + be0[i];
        }
        g_ws.c1[t] = (b1[t] - rm1[t]) * (g1[t] * rsqrtf(rv1[t] + 1e-5f)) + be1[t];
        if (t < 64)  { g_ws.nb1c[t] = nb1[t]; g_ws.db1c[t] = db1[t]; }
        if (t < 128) { g_ws.nb2c[t] = nb2[t]; g_ws.db2c[t] = db2[t]; }
        return;
    }

    const float* src; unsigned short* dst;
    const float* gp = nullptr; const float* rvp = nullptr;
    int sld, dld, k0, n0;
    if (b < 32)      { src = W1;  dst = (unsigned short*)g_ws.W1t;  sld = 256; dld = 512;
                       k0 = (b >> 2) * 64; n0 = (b & 3) * 64; gp = g1; rvp = rv1; }
    else if (b < 40) { src = W0;  dst = (unsigned short*)g_ws.W0t;  sld = 512; dld = 64;
                       k0 = 0; n0 = (b - 32) * 64; gp = g0; rvp = rv0; }
    else if (b < 44) { src = nW1; dst = (unsigned short*)g_ws.nW1t; sld = 64;  dld = 256;
                       k0 = (b - 40) * 64; n0 = 0; }
    else if (b < 48) { src = dW1; dst = (unsigned short*)g_ws.dW1t; sld = 64;  dld = 256;
                       k0 = (b - 44) * 64; n0 = 0; }
    else if (b < 50) { src = nW2; dst = (unsigned short*)g_ws.nW2t; sld = 128; dld = 64;
                       k0 = 0; n0 = (b - 48) * 64; }
    else             { src = dW2; dst = (unsigned short*)g_ws.dW2t; sld = 128; dld = 64;
                       k0 = 0; n0 = (b - 50) * 64; }

    __shared__ unsigned short tile[64][66];

    const int rr = t >> 4;
    const int cc = (t & 15) * 4;

#pragma unroll
    for (int g = 0; g < 4; ++g) {
        const int r = rr + g * 16;
        f32x4 v = *(const f32x4*)&src[(size_t)(k0 + r) * sld + n0 + cc];
        if (gp) {
            f32x4 gv = *(const f32x4*)&gp[n0 + cc];
            f32x4 rv = *(const f32x4*)&rvp[n0 + cc];
            v[0] *= gv[0] * rsqrtf(rv[0] + 1e-5f);
            v[1] *= gv[1] * rsqrtf(rv[1] + 1e-5f);
            v[2] *= gv[2] * rsqrtf(rv[2] + 1e-5f);
            v[3] *= gv[3] * rsqrtf(rv[3] + 1e-5f);
        }
        *(unsigned*)&tile[r][cc]     = (unsigned)f2bf(v[0]) | ((unsigned)f2bf(v[1]) << 16);
        *(unsigned*)&tile[r][cc + 2] = (unsigned)f2bf(v[2]) | ((unsigned)f2bf(v[3]) << 16);
    }
    __syncthreads();

#pragma unroll
    for (int g = 0; g < 4; ++g) {
        const int n = rr + g * 16;
        unsigned o01 = (unsigned)tile[cc + 0][n] | ((unsigned)tile[cc + 1][n] << 16);
        unsigned o23 = (unsigned)tile[cc + 2][n] | ((unsigned)tile[cc + 3][n] << 16);
        u32x2 o = { o01, o23 };
        *(u32x2*)&dst[(size_t)(n0 + n) * dld + k0 + cc] = o;
    }
}

// LEDGER: r15 (128 rows/block, skeleton amortized 2x) = first big win:
//   134 -> 120us fused, bench 275. But spill tripwire fired: FETCH 20->50,
//   WRITE 133->202 (~100MB scratch ~ 16us given back). L1 loop live set
//   was acc1[2][8](64) + ab[8](32) + wb[2](8) + addr > 128 budget.
// r16: ONE change vs r15 — L1 partial loop restructured mt-inner with a
//   single ab fragment live at a time: {wb[2]; for mt: ab -> 2 MFMAs}.
//   Live set ~85 < 128 -> spill-free. Verification signal: FETCH ~20MB,
//   WRITE ~133MB. Everything else byte-identical to r15.
__global__ __launch_bounds__(512, 4) void fused_mlp(
    const u32x4* __restrict__ xu, float* __restrict__ out)
{
    __shared__ __align__(16) unsigned short sXs[8 * 128 * 8];   // 16 KB (X, live to end)
    __shared__ __align__(16) unsigned short sH[32 * 128 * 8];   // 64 KB (H0 chunk / H1 / A)

    const int tid = threadIdx.x;
    const int w = tid >> 6;          // wave 0..7
    const int lane = tid & 63;
    const int m = lane & 15;
    const int q = lane >> 4;
    const int qh = q >> 1;
    const int ql = (q & 1) * 4;
    const int row0 = blockIdx.x * 128;

    // ---- stage X -> bf16 granule-major [g][r][8]; 2 units/thread ----
    {
        int r = tid >> 3, g = tid & 7;
#pragma unroll
        for (int hh = 0; hh < 2; ++hh) {
            int rr = r + hh * 64;
            u32x4 v0 = __builtin_nontemporal_load(&xu[(size_t)(row0 + rr) * 16 + g * 2]);
            u32x4 v1 = __builtin_nontemporal_load(&xu[(size_t)(row0 + rr) * 16 + g * 2 + 1]);
            u32x4 p = { pku(v0[1], v0[0]), pku(v0[3], v0[2]), pku(v1[1], v1[0]), pku(v1[3], v1[2]) };
            *(u32x4*)&sXs[(g * 128 + rr) * 8] = p;
        }
    }
    __syncthreads();   // B1

    // ---- layers 0+1, 2 K-chunks of 256; layer-1 partials in regs ----
    f32x4 acc1[2][8];
#pragma unroll
    for (int a = 0; a < 2; ++a)
#pragma unroll
        for (int b = 0; b < 8; ++b) acc1[a][b] = f32x4{0.f, 0.f, 0.f, 0.f};

    for (int ch = 0; ch < 2; ++ch) {
        // layer0: wave w -> chunk cols [w*32,+32), 128 rows
#pragma unroll
        for (int nt = 0; nt < 2; ++nt) {
            const int gcb = ch * 256 + w * 32 + nt * 16;
            bf16x8 wa0 = *(const bf16x8*)&g_ws.W0t[gcb + m][q * 8];
            bf16x8 wa1 = *(const bf16x8*)&g_ws.W0t[gcb + m][32 + q * 8];
            f32x4 bias = *(const f32x4*)&g_ws.c0[gcb + q * 4];
            const int kg = w * 4 + nt * 2 + qh;    // granule 0..31
#pragma unroll
            for (int mt = 0; mt < 8; ++mt) {
                bf16x8 xq0 = *(const bf16x8*)&sXs[(q * 128 + mt * 16 + m) * 8];
                bf16x8 xq1 = *(const bf16x8*)&sXs[((4 + q) * 128 + mt * 16 + m) * 8];
                f32x4 c = {0.f, 0.f, 0.f, 0.f};
                c = mfma16(wa0, xq0, c);
                c = mfma16(wa1, xq1, c);
                u32x2 pw = { pk(fmaxf(c[1] + bias[1], 0.f), fmaxf(c[0] + bias[0], 0.f)),
                             pk(fmaxf(c[3] + bias[3], 0.f), fmaxf(c[2] + bias[2], 0.f)) };
                *(u32x2*)&sH[(kg * 128 + mt * 16 + m) * 8 + ql] = pw;
            }
        }
        __syncthreads();   // B2 / B4

        // layer1 partial: wave w -> out cols [w*32,+32), K-chunk 256.
        // r16: mt-inner with ONE ab live -> live set ~85 regs, no spill.
#pragma unroll
        for (int ks = 0; ks < 8; ++ks) {
            bf16x8 wb0 = *(const bf16x8*)&g_ws.W1t[w * 32 + m][ch * 256 + ks * 32 + q * 8];
            bf16x8 wb1 = *(const bf16x8*)&g_ws.W1t[w * 32 + 16 + m][ch * 256 + ks * 32 + q * 8];
#pragma unroll
            for (int mt = 0; mt < 8; ++mt) {
                bf16x8 ab = *(const bf16x8*)&sH[((ks * 4 + q) * 128 + mt * 16 + m) * 8];
                acc1[0][mt] = mfma16(wb0, ab, acc1[0][mt]);
                acc1[1][mt] = mfma16(wb1, ab, acc1[1][mt]);
            }
        }
        __syncthreads();   // B3 / B5
    }

    // ---- H1 = relu(acc1 + c1) -> sH (whole chunk region dead after B5) ----
#pragma unroll
    for (int nt = 0; nt < 2; ++nt) {
        const int cb = w * 32 + nt * 16;
        f32x4 bias = *(const f32x4*)&g_ws.c1[cb + q * 4];
        const int kg = w * 4 + nt * 2 + qh;    // granule 0..31
#pragma unroll
        for (int mt = 0; mt < 8; ++mt) {
            f32x4 c = acc1[nt][mt];
            u32x2 pw = { pk(fmaxf(c[1] + bias[1], 0.f), fmaxf(c[0] + bias[0], 0.f)),
                         pk(fmaxf(c[3] + bias[3], 0.f), fmaxf(c[2] + bias[2], 0.f)) };
            *(u32x2*)&sH[(kg * 128 + mt * 16 + m) * 8 + ql] = pw;
        }
    }
    __syncthreads();   // B6

    // ---- head layer 1: head = w>>2, cols (w&3)*16..+16, K=256, 128 rows ----
    const int head = w >> 2;
    {
        const int cb = (w & 3) * 16;
        const unsigned short (*Wh)[256] = head ? g_ws.dW1t : g_ws.nW1t;
        const float* bh = head ? g_ws.db1c : g_ws.nb1c;
        f32x4 acc[8];
#pragma unroll
        for (int b = 0; b < 8; ++b) acc[b] = f32x4{0.f, 0.f, 0.f, 0.f};
#pragma unroll
        for (int ks = 0; ks < 8; ++ks) {
            bf16x8 wh = *(const bf16x8*)&Wh[cb + m][ks * 32 + q * 8];
#pragma unroll
            for (int mt = 0; mt < 8; ++mt) {
                bf16x8 ab = *(const bf16x8*)&sH[((ks * 4 + q) * 128 + mt * 16 + m) * 8];
                acc[mt] = mfma16(wh, ab, acc[mt]);
            }
        }
        // all waves' H1 reads must finish before A overlays sH
        __syncthreads();   // B7
        unsigned short* Ah = sH + head * 8192;   // An @ [0,16KB), Ad @ [16KB,32KB)
        f32x4 bias = *(const f32x4*)&bh[cb + q * 4];
        const int kg = (w & 3) * 2 + qh;         // granule 0..7 within head's A
#pragma unroll
        for (int mt = 0; mt < 8; ++mt) {
            f32x4 c = acc[mt];
            u32x2 pw = { pk(fmaxf(c[1] + bias[1], 0.f), fmaxf(c[0] + bias[0], 0.f)),
                         pk(fmaxf(c[3] + bias[3], 0.f), fmaxf(c[2] + bias[2], 0.f)) };
            *(u32x2*)&Ah[(kg * 128 + mt * 16 + m) * 8 + ql] = pw;
        }
    }
    __syncthreads();   // B8

    // ---- head layer 2 + mask + plain dwordx4 stores ----
    {
        const unsigned short (*W2)[64] = head ? g_ws.dW2t : g_ws.nW2t;
        const float* b2 = head ? g_ws.db2c : g_ws.nb2c;
        const unsigned short* Ah = sH + head * 8192;
        float* op = out + (size_t)head * (size_t)NB * 128;

        // thresholds via PROVEN sXs path: granule 7 elems 4,5 = cols 60,61
        // (class ids 0..127 exact in bf16); sXs untouched throughout
        int thr[8];
#pragma unroll
        for (int mt = 0; mt < 8; ++mt) {
            unsigned tv = *(const unsigned*)&sXs[(7 * 128 + mt * 16 + m) * 8 + 4];
            thr[mt] = (int)__builtin_bit_cast(float, head ? (tv & 0xffff0000u) : (tv << 16));
        }
#pragma unroll
        for (int ct = 0; ct < 2; ++ct) {
            const int ocb = (w & 3) * 32 + ct * 16;
            bf16x8 w0 = *(const bf16x8*)&W2[ocb + m][q * 8];
            bf16x8 w1 = *(const bf16x8*)&W2[ocb + m][32 + q * 8];
            f32x4 bias = *(const f32x4*)&b2[ocb + q * 4];
#pragma unroll
            for (int mt = 0; mt < 8; ++mt) {
                bf16x8 a0 = *(const bf16x8*)&Ah[(q * 128 + mt * 16 + m) * 8];
                bf16x8 a1 = *(const bf16x8*)&Ah[((4 + q) * 128 + mt * 16 + m) * 8];
                f32x4 c = {0.f, 0.f, 0.f, 0.f};
                c = mfma16(w0, a0, c);
                c = mfma16(w1, a1, c);
                const int ci = ocb + q * 4;
                const int t = thr[mt];
                f32x4 v;
                v[0] = (ci + 0 <= t) ? c[0] + bias[0] : NEG9;
                v[1] = (ci + 1 <= t) ? c[1] + bias[1] : NEG9;
                v[2] = (ci + 2 <= t) ? c[2] + bias[2] : NEG9;
                v[3] = (ci + 3 <= t) ? c[3] + bias[3] : NEG9;
                *(f32x4*)&op[(size_t)(row0 + mt * 16 + m) * 128 + ci] = v;
            }
        }
    }
}

extern "C" void kernel_launch(void* const* d_in, const int* in_sizes, int n_in,
                              void* d_out, int out_size, void* d_ws, size_t ws_size,
                              hipStream_t stream) {
    (void)in_sizes; (void)n_in; (void)d_ws; (void)ws_size;

    prep_kernel<<<53, 256, 0, stream>>>(
        (const float*)d_in[1], (const float*)d_in[2], (const float*)d_in[3],
        (const float*)d_in[4], (const float*)d_in[5], (const float*)d_in[6],
        (const float*)d_in[7], (const float*)d_in[8], (const float*)d_in[9],
        (const float*)d_in[10], (const float*)d_in[11], (const float*)d_in[12],
        (const float*)d_in[13], (const float*)d_in[14], (const float*)d_in[15],
        (const float*)d_in[16], (const float*)d_in[17], (const float*)d_in[18],
        (const float*)d_in[19], (const float*)d_in[20]);

    fused_mlp<<<NB / 128, 512, 0, stream>>>((const u32x4*)d_in[0], (float*)d_out);
}